// Round 5
// baseline (2061.432 us; speedup 1.0000x reference)
//
#include <hip/hip_runtime.h>
#include <math.h>

// ---------------------------------------------------------------------------
// KimiDeltaAttention B=4 T=2048 HID=2048 H=16 DK=DV=128
//  - one fused QKV bf16 MFMA GEMM (N=6144) with silu+l2norm in epilogue
//  - one fused lowrank GEMM (fpre|gpre|beta, N=384 padded)
//  - scan v9: 32-way k-split x 2 cols/lane. Per step each lane reads 16B per
//    stream -> 3 ds_read_b128 (was 6), 32 distinct chunks, even bank spread,
//    NO swizzle (linear stage + linear read). Cross-32 reduction finish via
//    permlane32_swap dual-input trick (VALU pipe; lgkm accounting untouched).
//    Same 4-slot/8-step pipeline and identical vmcnt peel as v8.
// ---------------------------------------------------------------------------

typedef short short8 __attribute__((ext_vector_type(8)));
typedef float f32x4 __attribute__((ext_vector_type(4)));
typedef float f32x2 __attribute__((ext_vector_type(2)));
typedef int int2v __attribute__((ext_vector_type(2)));
typedef unsigned short ushort_t;

// gemm epilogue modes
enum { M_PLAIN = 0, M_QKV = 1, M_LOWRANK = 2, M_GATE = 3, M_FACTOR = 4 };

__device__ __forceinline__ unsigned short f32_to_bf16(float f) {
  unsigned int u = __float_as_uint(f);
  u += 0x7FFFu + ((u >> 16) & 1u);   // RNE
  return (unsigned short)(u >> 16);
}

__device__ __forceinline__ float silu(float x) { return x / (1.f + __expf(-x)); }

__device__ __forceinline__ void gld_lds16(const void* g, void* l) {
  __builtin_amdgcn_global_load_lds(
      (const __attribute__((address_space(1))) unsigned int*)g,
      (__attribute__((address_space(3))) unsigned int*)l, 16, 0, 0);
}

// sum across each aligned 16-lane group, pure DPP (compiler handles hazards)
__device__ __forceinline__ float row16_sum(float x) {
  x += __int_as_float(__builtin_amdgcn_update_dpp(0, __float_as_int(x), 0xB1, 0xF, 0xF, true));
  x += __int_as_float(__builtin_amdgcn_update_dpp(0, __float_as_int(x), 0x4E, 0xF, 0xF, true));
  x += __int_as_float(__builtin_amdgcn_update_dpp(0, __float_as_int(x), 0x141, 0xF, 0xF, true));
  x += __int_as_float(__builtin_amdgcn_update_dpp(0, __float_as_int(x), 0x140, 0xF, 0xF, true));
  return x;
}

// sum over the 32-lane group {16-row r, 16-row r^2}: row16 then cross-32 via
// permlane32_swap with both inputs = x. Under any half-exchange semantics the
// pair (a',b') holds {lo,lo}/{hi,hi} arrangements s.t. a'+b' = x[i&~32]+x[i|32]
// in every lane -> broadcast 32-group sum.
__device__ __forceinline__ float sum32(float x) {
  x = row16_sum(x);
  int2v r = __builtin_amdgcn_permlane32_swap(__float_as_int(x), __float_as_int(x),
                                             false, false);
  return __int_as_float(r.x) + __int_as_float(r.y);
}

// ---------------------------------------------------------------------------
// bf16 MFMA GEMM, 128x128 tile, m97 structure + mode-switched epilogue.
// ---------------------------------------------------------------------------
__global__ __launch_bounds__(256) void gemm_bf16(
    const ushort_t* __restrict__ A, const ushort_t* __restrict__ W,
    int M, int N, int K, int mode,
    float* __restrict__ f0, float* __restrict__ f1, float* __restrict__ f2,
    ushort_t* __restrict__ b0, ushort_t* __restrict__ b1,
    const float* __restrict__ bias, const float* __restrict__ A_log,
    const float* __restrict__ dt_bias) {
  __shared__ alignas(16) ushort_t As[4096];
  __shared__ alignas(16) ushort_t Bs[4096];
  __shared__ float l2s[2][128];
  const int tid = threadIdx.x;
  const int wv = tid >> 6, ln = tid & 63;
  const int bm = blockIdx.y * 128, bn = blockIdx.x * 128;
  const int wm = wv >> 1, wn = wv & 1;

  const int srow = tid >> 2;
  const int skg = (tid & 3) ^ ((srow >> 1) & 3);
  const size_t ag0 = (size_t)(bm + srow) * K + skg * 8;
  const size_t ag1 = ag0 + (size_t)64 * K;
  const size_t bg0 = (size_t)(bn + srow) * K + skg * 8;
  const size_t bg1 = bg0 + (size_t)64 * K;
  char* const lA = (char*)As;
  char* const lB = (char*)Bs;
  const int wbase = wv * 1024;

  const int fr = ln & 15, fq = ln >> 4;
  const int pg = fq ^ ((fr >> 1) & 3);
  int aoff[4], boff[4];
#pragma unroll
  for (int i = 0; i < 4; i++) {
    aoff[i] = (wm * 64 + i * 16 + fr) * 64 + pg * 16;
    boff[i] = (wn * 64 + i * 16 + fr) * 64 + pg * 16;
  }

  f32x4 acc[4][4];
#pragma unroll
  for (int i = 0; i < 4; i++)
#pragma unroll
    for (int j = 0; j < 4; j++) {
      acc[i][j][0] = 0.f; acc[i][j][1] = 0.f; acc[i][j][2] = 0.f; acc[i][j][3] = 0.f;
    }

  for (int k0 = 0; k0 < K; k0 += 32) {
    gld_lds16(A + ag0 + k0, lA + wbase);
    gld_lds16(A + ag1 + k0, lA + 4096 + wbase);
    gld_lds16(W + bg0 + k0, lB + wbase);
    gld_lds16(W + bg1 + k0, lB + 4096 + wbase);
    __syncthreads();
    short8 af[4], bf[4];
#pragma unroll
    for (int i = 0; i < 4; i++) af[i] = *(const short8*)(lA + aoff[i]);
#pragma unroll
    for (int i = 0; i < 4; i++) bf[i] = *(const short8*)(lB + boff[i]);
#pragma unroll
    for (int i = 0; i < 4; i++)
#pragma unroll
      for (int j = 0; j < 4; j++)
        acc[i][j] = __builtin_amdgcn_mfma_f32_16x16x32_bf16(af[i], bf[j], acc[i][j], 0, 0, 0);
    __syncthreads();
  }

  // C/D layout: col = ln&15, row = (ln>>4)*4 + reg
  const int cc = ln & 15, cq = ln >> 4;

  if (mode == M_QKV) {
    // silu in place
#pragma unroll
    for (int i = 0; i < 4; i++)
#pragma unroll
      for (int j = 0; j < 4; j++)
#pragma unroll
        for (int r = 0; r < 4; r++) acc[i][j][r] = silu(acc[i][j][r]);
    const bool isqk = (bn < 4096);
    float invr[4][4];
    if (isqk) {
      const float scale = (bn < 2048) ? 0.08838834764831845f : 1.0f;
#pragma unroll
      for (int i = 0; i < 4; i++)
#pragma unroll
        for (int r = 0; r < 4; r++) {
          float ss = 0.f;
#pragma unroll
          for (int j = 0; j < 4; j++) ss = fmaf(acc[i][j][r], acc[i][j][r], ss);
          ss = row16_sum(ss);
          if (cc == 0) l2s[wn][wm * 64 + i * 16 + cq * 4 + r] = ss;
        }
      __syncthreads();
#pragma unroll
      for (int i = 0; i < 4; i++)
#pragma unroll
        for (int r = 0; r < 4; r++) {
          const int rl = wm * 64 + i * 16 + cq * 4 + r;
          invr[i][r] = rsqrtf(l2s[0][rl] + l2s[1][rl] + 1e-6f) * scale;
        }
    } else {
#pragma unroll
      for (int i = 0; i < 4; i++)
#pragma unroll
        for (int r = 0; r < 4; r++) invr[i][r] = 1.f;
    }
    float* dst = (bn < 2048) ? f0 : ((bn < 4096) ? f1 : f2);
    const int nb = bn & 2047;
#pragma unroll
    for (int i = 0; i < 4; i++)
#pragma unroll
      for (int r = 0; r < 4; r++) {
        const int gm = bm + wm * 64 + i * 16 + cq * 4 + r;
#pragma unroll
        for (int j = 0; j < 4; j++) {
          const int gn = nb + wn * 64 + j * 16 + cc;
          dst[(size_t)gm * 2048 + gn] = acc[i][j][r] * invr[i][r];
        }
      }
    return;
  }

  if (mode == M_LOWRANK) {
#pragma unroll
    for (int i = 0; i < 4; i++)
#pragma unroll
      for (int r = 0; r < 4; r++) {
        const int gm = bm + wm * 64 + i * 16 + cq * 4 + r;
#pragma unroll
        for (int j = 0; j < 4; j++) {
          const int gn = bn + wn * 64 + j * 16 + cc;
          const float x = acc[i][j][r];
          if (gn < 128) b0[(size_t)gm * 128 + gn] = f32_to_bf16(x);
          else if (gn < 256) b1[(size_t)gm * 128 + (gn - 128)] = f32_to_bf16(x);
          else if (gn < 272) f0[(size_t)gm * 16 + (gn - 256)] = 1.f / (1.f + __expf(-x));
        }
      }
    return;
  }

  // M_PLAIN / M_GATE / M_FACTOR -> f32, stride N
#pragma unroll
  for (int i = 0; i < 4; i++)
#pragma unroll
    for (int r = 0; r < 4; r++) {
      const int gm = bm + wm * 64 + i * 16 + cq * 4 + r;
#pragma unroll
      for (int j = 0; j < 4; j++) {
        const int gn = bn + wn * 64 + j * 16 + cc;
        float x = acc[i][j][r];
        if (mode == M_FACTOR) x += bias[gn];
        else if (mode == M_GATE) {
          const float y = x + dt_bias[gn];
          const float sp = fmaxf(y, 0.f) + log1pf(__expf(-fabsf(y)));
          x = __expf(-__expf(A_log[gn >> 7]) * sp);
        }
        f0[(size_t)gm * N + gn] = x;
      }
    }
}

__global__ __launch_bounds__(256) void cast_bf16(const float* __restrict__ x,
                                                 ushort_t* __restrict__ y, int n) {
  const int i = (blockIdx.x * 256 + threadIdx.x) * 4;
  if (i >= n) return;
  const float4 v = *(const float4*)&x[i];
  union { ushort_t u[4]; uint2 v2; } o;
  o.u[0] = f32_to_bf16(v.x); o.u[1] = f32_to_bf16(v.y);
  o.u[2] = f32_to_bf16(v.z); o.u[3] = f32_to_bf16(v.w);
  *(uint2*)&y[i] = o.v2;
}

// ---------------------------------------------------------------------------
// Barrier-free gated delta-rule scan, v9. LDS-staged k/q/g, 32-way k-split,
// 2 cols/lane, all-SALU addressing, permlane cross-32 reductions.
// grid = 2048 (64 bh x 32 colgroups, XCD-swizzled), block = 64 (one wave).
// Lane: cl = (ln>>4)&1, kg5 = (ln&15)|(((ln>>5)&1)<<4).
//   lane covers cols {cg*4+cl*2, +1} and k-slice [kg5*4, kg5*4+4).
//   S2[4] = f32x2 per k (cols pair). Reads: 1 ds_read_b128 per stream/step.
// LDS: 4 slots x 3 streams x 1KB (2 steps/slot) = 12KB, 8-step horizon,
// linear layout both sides (32 distinct 16B chunks -> even bank spread).
// vmcnt peel identical to v8 (same VMEM op counts); lgkm wait 6 -> 3.
// ---------------------------------------------------------------------------
__global__ __launch_bounds__(64, 2) void kda_scan(
    const float* __restrict__ q, const float* __restrict__ k,
    const float* __restrict__ v, const float* __restrict__ ge,
    const float* __restrict__ beta, const float* __restrict__ S0,
    float* __restrict__ o, float* __restrict__ S_out) {
  const int bid = blockIdx.x;
  const int bh = (((bid >> 3) & 7) << 3) | (bid & 7);
  const int cg = bid >> 6;
  const int h = bh & 15, b = bh >> 4;
  const int ln = threadIdx.x;
  const int cl = (ln >> 4) & 1;
  const int kg5 = (ln & 15) | (((ln >> 5) & 1) << 4);
  const int col0 = cg * 4 + cl * 2;      // first of this lane's 2 columns
  const int k0i = kg5 * 4;               // first k index of this lane's slice

  __shared__ alignas(16) char lds[12288];

  const size_t s_base = (size_t)bh * (128 * 128);
  const size_t rb = (size_t)b * (2048 * 2048) + (size_t)h * 128;
  const size_t bbase = (size_t)(b * 2048) * 16 + h;

  // uniform bases, advanced in SALU inside the loop
  const char* kc = (const char*)(k + rb);
  const char* qc = (const char*)(q + rb);
  const char* gc = (const char*)(ge + rb);
  const float* vbp  = v + rb;            // step-even v row
  const float* vbp2 = vbp + 2048;        // step-odd v row
  const float* bbp  = beta + bbase;
  const float* bbp2 = bbp + 16;
  float* obp  = o + rb;                  // step-even o row
  float* obp2 = obp + 2048;              // step-odd o row
  const float* S0b = S0 + s_base;

  // linear staging: lanes 0-31 -> row even bytes 0-511, lanes 32-63 -> row odd
  const unsigned lane_src = (unsigned)((ln >> 5) * 8192 + (ln & 31) * 16);
  // linear read: this lane's 16B k-slice within a 512B row
  const unsigned rdK = (unsigned)(kg5 * 16);

  // fixed per-lane voffsets
  const unsigned voff_v = (unsigned)(col0 * 4);   // dwordx2
  const unsigned voff_b = 0u;
  const unsigned voff_o = (unsigned)(col0 * 4);   // dwordx2

  // ---- initial state via asm loads (4 x dwordx2: k-slice x col pair) ------
  f32x2 S2[4];
#pragma unroll
  for (int j = 0; j < 4; ++j) {
    const unsigned offs = (unsigned)(((k0i + j) * 128 + col0) * 4);
    asm volatile("global_load_dwordx2 %0, %1, %2" : "=v"(S2[j]) : "v"(offs), "s"(S0b));
  }

  f32x2 Vs2[8], Os2[8];
  float Bs[8];
  f32x4 Ka, Qa, Ga;
  f32x4 Kb, Qb, Gb;

#define WAITV(N) do { asm volatile("s_waitcnt vmcnt(" #N ")" ::: "memory"); \
                      __builtin_amdgcn_sched_barrier(0); } while (0)
#define WAITL(N) do { asm volatile("s_waitcnt lgkmcnt(" #N ")" ::: "memory"); \
                      __builtin_amdgcn_sched_barrier(0); } while (0)
#define DSR(dst, a, IMM) \
  asm volatile("ds_read_b128 %0, %1 offset:%c2" : "=v"(dst) : "v"(a), "n"(IMM))

// 3 ds_reads for one step: slot SL, phase PH, into fragment suffix SFX
#define READS(SFX, SL, PH)                                    \
  do {                                                        \
    DSR(K##SFX, rdK, ((SL)*3 + 0) * 1024 + (PH)*512);         \
    DSR(Q##SFX, rdK, ((SL)*3 + 1) * 1024 + (PH)*512);         \
    DSR(G##SFX, rdK, ((SL)*3 + 2) * 1024 + (PH)*512);         \
  } while (0)

// stage slot SL for the next 2 rows; 7 VMEM ops; bases advance via SALU
#define STAGE(SL)                                                                                    \
  do {                                                                                               \
    gld_lds16(kc + lane_src, lds + ((SL)*3 + 0) * 1024); kc += 16384;                                \
    gld_lds16(qc + lane_src, lds + ((SL)*3 + 1) * 1024); qc += 16384;                                \
    gld_lds16(gc + lane_src, lds + ((SL)*3 + 2) * 1024); gc += 16384;                                \
    asm volatile("global_load_dwordx2 %0, %1, %2" : "=v"(Vs2[2*(SL)])   : "v"(voff_v), "s"(vbp));    \
    asm volatile("global_load_dwordx2 %0, %1, %2" : "=v"(Vs2[2*(SL)+1]) : "v"(voff_v), "s"(vbp2));   \
    vbp += 4096; vbp2 += 4096;                                                                       \
    asm volatile("global_load_dword %0, %1, %2" : "=v"(Bs[2*(SL)])   : "v"(voff_b), "s"(bbp));       \
    asm volatile("global_load_dword %0, %1, %2" : "=v"(Bs[2*(SL)+1]) : "v"(voff_b), "s"(bbp2));      \
    bbp += 32; bbp2 += 32;                                                                           \
  } while (0)

#define STORES(U)                                                                                    \
  do {                                                                                               \
    if ((ln & 47) == 0) {                                                                            \
      asm volatile("global_store_dwordx2 %0, %1, %2" :: "v"(voff_o), "v"(Os2[(U)-1]), "s"(obp) : "memory");  \
      asm volatile("global_store_dwordx2 %0, %1, %2" :: "v"(voff_o), "v"(Os2[(U)]), "s"(obp2) : "memory");   \
    }                                                                                                \
    obp += 4096; obp2 += 4096;                                                                       \
  } while (0)

#define COMPUTE(F, U)                                                                                \
  do {                                                                                               \
    S2[0] *= G##F[0]; S2[1] *= G##F[1]; S2[2] *= G##F[2]; S2[3] *= G##F[3];                          \
    float p0 = K##F[0] * S2[0].x;  float p1 = K##F[0] * S2[0].y;                                     \
    float o0 = Q##F[0] * S2[0].x;  float o1 = Q##F[0] * S2[0].y;                                     \
    float d  = Q##F[0] * K##F[0];                                                                    \
    p0 = fmaf(K##F[1], S2[1].x, p0); p1 = fmaf(K##F[1], S2[1].y, p1);                                \
    o0 = fmaf(Q##F[1], S2[1].x, o0); o1 = fmaf(Q##F[1], S2[1].y, o1);                                \
    d  = fmaf(Q##F[1], K##F[1], d);                                                                  \
    p0 = fmaf(K##F[2], S2[2].x, p0); p1 = fmaf(K##F[2], S2[2].y, p1);                                \
    o0 = fmaf(Q##F[2], S2[2].x, o0); o1 = fmaf(Q##F[2], S2[2].y, o1);                                \
    d  = fmaf(Q##F[2], K##F[2], d);                                                                  \
    p0 = fmaf(K##F[3], S2[3].x, p0); p1 = fmaf(K##F[3], S2[3].y, p1);                                \
    o0 = fmaf(Q##F[3], S2[3].x, o0); o1 = fmaf(Q##F[3], S2[3].y, o1);                                \
    d  = fmaf(Q##F[3], K##F[3], d);                                                                  \
    p0 = sum32(p0); p1 = sum32(p1);                                                                  \
    o0 = sum32(o0); o1 = sum32(o1);                                                                  \
    d  = sum32(d);                                                                                   \
    const float dl0 = (Vs2[(U)].x - p0) * Bs[(U)];                                                   \
    const float dl1 = (Vs2[(U)].y - p1) * Bs[(U)];                                                   \
    Os2[(U)].x = fmaf(d, dl0, o0);                                                                   \
    Os2[(U)].y = fmaf(d, dl1, o1);                                                                   \
    S2[0].x = fmaf(K##F[0], dl0, S2[0].x); S2[0].y = fmaf(K##F[0], dl1, S2[0].y);                    \
    S2[1].x = fmaf(K##F[1], dl0, S2[1].x); S2[1].y = fmaf(K##F[1], dl1, S2[1].y);                    \
    S2[2].x = fmaf(K##F[2], dl0, S2[2].x); S2[2].y = fmaf(K##F[2], dl1, S2[2].y);                    \
    S2[3].x = fmaf(K##F[3], dl0, S2[3].x); S2[3].y = fmaf(K##F[3], dl1, S2[3].y);                    \
  } while (0)

// even step U (slot SL): issue reads for U+1 (phase 1), compute U from 'a'
#define STEP_EVEN(U, SL) \
  do { READS(b, SL, 1); WAITL(3); COMPUTE(a, U); } while (0)
// odd step U (slot SL): wait, issue next-slot phase-0 reads, compute U from
// 'b', restage SL (+8 steps ahead), batch-store Os2[U-1],Os2[U]
#define STEP_ODD(U, SL, NSL, WV) \
  do { WAITV(WV); READS(a, NSL, 0); WAITL(3); COMPUTE(b, U); STAGE(SL); STORES(U); } while (0)

#define ITER(W1, W3, W5, W7)                          \
  do {                                                \
    STEP_EVEN(0, 0);                                  \
    STEP_ODD(1, 0, 1, W1);                            \
    STEP_EVEN(2, 1);                                  \
    STEP_ODD(3, 1, 2, W3);                            \
    STEP_EVEN(4, 2);                                  \
    STEP_ODD(5, 2, 3, W5);                            \
    STEP_EVEN(6, 3);                                  \
    STEP_ODD(7, 3, 0, W7);                            \
  } while (0)

  // ---- prologue: stage slots 0..3 (steps 0..7), wait slot0, prime reads ---
  STAGE(0);
  STAGE(1);
  STAGE(2);
  STAGE(3);
  WAITV(21);               // drains S0(4)+slot0(7); keeps slots 1-3 (21)
  READS(a, 0, 0);          // step 0 fragments

  ITER(14, 16, 18, 20);    // peeled first iteration (prologue FIFO spacing)
  for (int it = 1; it < 256; ++it) {
    ITER(20, 20, 20, 20);
  }
  // final iteration's restages/reads over-run into adjacent allocated
  // workspace/output regions (<=64KB) and are never consumed.

  // drain everything before the compiler may reuse destination VGPRs
  WAITL(0);
  WAITV(0);

#pragma unroll
  for (int j = 0; j < 4; ++j)
    *(f32x2*)&S_out[s_base + (size_t)(k0i + j) * 128 + col0] = S2[j];

#undef ITER
#undef STEP_ODD
#undef STEP_EVEN
#undef COMPUTE
#undef STORES
#undef STAGE
#undef READS
#undef DSR
#undef WAITL
#undef WAITV
}

// out_bf16 = rms(o)*w*sigmoid(factor). grid 2048 x 256: 64 rows/block.
__global__ __launch_bounds__(256) void gate_rmsnorm(
    const float* __restrict__ o, const float* __restrict__ factor,
    const float* __restrict__ w, ushort_t* __restrict__ out) {
  const int ln = threadIdx.x & 63, wv = threadIdx.x >> 6;
  const float w0 = w[ln * 2], w1 = w[ln * 2 + 1];
  const size_t row0 = (size_t)blockIdx.x * 64 + wv * 16;
  for (int it = 0; it < 16; it++) {
    const size_t base = (row0 + it) * 128 + ln * 2;
    const float2 x = *(const float2*)&o[base];
    const float2 f = *(const float2*)&factor[base];
    float ss = fmaf(x.x, x.x, x.y * x.y);
    ss = row16_sum(ss);
    ss += __shfl_xor(ss, 16);
    ss += __shfl_xor(ss, 32);
    const float r = rsqrtf(ss * (1.f / 128.f) + 1e-5f);
    const float y0 = x.x * r * w0 / (1.f + __expf(-f.x));
    const float y1 = x.y * r * w1 / (1.f + __expf(-f.y));
    *(unsigned int*)&out[base] =
        (unsigned int)f32_to_bf16(y0) | ((unsigned int)f32_to_bf16(y1) << 16);
  }
}

extern "C" void kernel_launch(void* const* d_in, const int* in_sizes, int n_in,
                              void* d_out, int out_size, void* d_ws, size_t ws_size,
                              hipStream_t stream) {
  const float* h    = (const float*)d_in[0];
  const float* S0   = (const float*)d_in[1];
  const float* q_w  = (const float*)d_in[2];
  const float* k_w  = (const float*)d_in[3];
  const float* v_w  = (const float*)d_in[4];
  const float* f_w0 = (const float*)d_in[5];
  const float* f_w1 = (const float*)d_in[6];
  const float* b_w  = (const float*)d_in[7];
  const float* A_log  = (const float*)d_in[8];
  const float* dt_b   = (const float*)d_in[9];
  const float* g_w0 = (const float*)d_in[10];
  const float* g_w1 = (const float*)d_in[11];
  const float* g_b1 = (const float*)d_in[12];
  const float* o_nw = (const float*)d_in[13];
  const float* o_w  = (const float*)d_in[14];

  float* outp = (float*)d_out;                 // exp(g) -> factor -> final out
  float* Sout = outp + (size_t)8192 * 2048;

  const size_t BIG = (size_t)8192 * 2048;   // 16.8M elems
  float* ws = (float*)d_ws;
  float* vbuf  = ws;                         // f32 [BIG]
  float* qbuf  = vbuf + BIG;                 // f32 [BIG]; gated bf16 reuses this
  float* kbuf  = qbuf + BIG;                 // f32 [BIG]
  float* betab = kbuf + BIG;                 // f32 [8192*16]
  ushort_t* fpreb = (ushort_t*)(betab + (size_t)8192 * 16);   // bf16 [8192*128]
  ushort_t* gpreb = fpreb + (size_t)8192 * 128;
  ushort_t* wf1   = gpreb + (size_t)8192 * 128;               // [2048*128]
  ushort_t* wg1   = wf1 + (size_t)2048 * 128;
  ushort_t* wo    = wg1 + (size_t)2048 * 128;                 // [2048*2048]
  ushort_t* wlow  = wo + (size_t)2048 * 2048;                 // [384*2048]
  ushort_t* hb    = wlow + (size_t)384 * 2048;                // [BIG] bf16
  ushort_t* wqkv  = hb + BIG;                                 // [6144*2048] bf16
  // obuf (scan output, f32 BIG) aliases [hb | wqkv | pad] — all dead pre-scan
  float* obuf = (float*)hb;
  ushort_t* gatedb = (ushort_t*)qbuf;        // bf16 gated o (qbuf dead post-scan)

  const dim3 blk(256);

  // casts
  cast_bf16<<<16384, blk, 0, stream>>>(h, hb, 8192 * 2048);
  cast_bf16<<<4096, blk, 0, stream>>>(q_w, wqkv, 2048 * 2048);
  cast_bf16<<<4096, blk, 0, stream>>>(k_w, wqkv + (size_t)2048 * 2048, 2048 * 2048);
  cast_bf16<<<4096, blk, 0, stream>>>(v_w, wqkv + (size_t)4096 * 2048, 2048 * 2048);
  cast_bf16<<<4096, blk, 0, stream>>>(o_w, wo, 2048 * 2048);
  cast_bf16<<<256, blk, 0, stream>>>(f_w0, wlow, 128 * 2048);
  cast_bf16<<<256, blk, 0, stream>>>(g_w0, wlow + (size_t)128 * 2048, 128 * 2048);
  cast_bf16<<<32, blk, 0, stream>>>(b_w, wlow + (size_t)256 * 2048, 16 * 2048);
  cast_bf16<<<256, blk, 0, stream>>>(f_w1, wf1, 2048 * 128);
  cast_bf16<<<256, blk, 0, stream>>>(g_w1, wg1, 2048 * 128);

  // fused QKV projection: silu(+l2norm for q/k) -> qbuf/kbuf/vbuf f32
  gemm_bf16<<<dim3(48, 64), blk, 0, stream>>>(hb, wqkv, 8192, 6144, 2048, M_QKV,
      qbuf, kbuf, vbuf, nullptr, nullptr, nullptr, nullptr, nullptr);
  // fused lowrank: fpre|gpre (bf16) + beta (sigmoid f32)
  gemm_bf16<<<dim3(3, 64), blk, 0, stream>>>(hb, wlow, 8192, 384, 2048, M_LOWRANK,
      betab, nullptr, nullptr, fpreb, gpreb, nullptr, nullptr, nullptr);
  // exp(g) -> outp
  gemm_bf16<<<dim3(16, 64), blk, 0, stream>>>(fpreb, wf1, 8192, 2048, 128, M_GATE,
      outp, nullptr, nullptr, nullptr, nullptr, nullptr, A_log, dt_b);
  // scan: o -> obuf (hb/wqkv region dead), S -> d_out tail
  kda_scan<<<2048, 64, 0, stream>>>(qbuf, kbuf, vbuf, outp, betab, S0, obuf, Sout);
  // factor = gpre @ g_w1.T + g_b1 -> outp (exp(g) dead)
  gemm_bf16<<<dim3(16, 64), blk, 0, stream>>>(gpreb, wg1, 8192, 2048, 128, M_FACTOR,
      outp, nullptr, nullptr, nullptr, nullptr, g_b1, nullptr, nullptr);
  // gated rmsnorm -> bf16 into gatedb (qbuf region)
  gate_rmsnorm<<<2048, blk, 0, stream>>>(obuf, outp, o_nw, gatedb);
  // out = gated_o @ o_w.T -> outp
  gemm_bf16<<<dim3(16, 64), blk, 0, stream>>>(gatedb, wo, 8192, 2048, 2048, M_PLAIN,
      outp, nullptr, nullptr, nullptr, nullptr, nullptr, nullptr, nullptr);
}

// Round 6
// 1741.768 us; speedup vs baseline: 1.1835x; 1.1835x over previous
//
#include <hip/hip_runtime.h>
#include <math.h>

// ---------------------------------------------------------------------------
// KimiDeltaAttention B=4 T=2048 HID=2048 H=16 DK=DV=128
//  - one fused QKV bf16 MFMA GEMM (N=6144), silu+l2norm epilogue; q,k stored
//    BF16 (l2-normed, unbiased 0.2% rounding; g stays f32 for decay safety)
//  - one fused lowrank GEMM (fpre|gpre|beta, N=384 padded)
//  - scan v10: v8 skeleton (16-way k-split, 4 cols/wave, 3 DPP reductions,
//    all-SALU addressing) with bf16 k/q: 4 ds_read_b128/step (was 6), 4-step
//    slots (16-step horizon, 16KB LDS), 12 VMEM/slot, counted vmcnt
//    (peel 24/28/32/36 -> steady 36), lgkm wait 4.
// ---------------------------------------------------------------------------

typedef short short8 __attribute__((ext_vector_type(8)));
typedef float f32x4 __attribute__((ext_vector_type(4)));
typedef int int4v __attribute__((ext_vector_type(4)));
typedef unsigned short ushort_t;

// gemm epilogue modes
enum { M_PLAIN = 0, M_QKV = 1, M_LOWRANK = 2, M_GATE = 3, M_FACTOR = 4 };

__device__ __forceinline__ unsigned short f32_to_bf16(float f) {
  unsigned int u = __float_as_uint(f);
  u += 0x7FFFu + ((u >> 16) & 1u);   // RNE
  return (unsigned short)(u >> 16);
}

__device__ __forceinline__ float silu(float x) { return x / (1.f + __expf(-x)); }

__device__ __forceinline__ void gld_lds16(const void* g, void* l) {
  __builtin_amdgcn_global_load_lds(
      (const __attribute__((address_space(1))) unsigned int*)g,
      (__attribute__((address_space(3))) unsigned int*)l, 16, 0, 0);
}

// sum across each aligned 16-lane group, pure DPP (compiler handles hazards)
__device__ __forceinline__ float row16_sum(float x) {
  x += __int_as_float(__builtin_amdgcn_update_dpp(0, __float_as_int(x), 0xB1, 0xF, 0xF, true));
  x += __int_as_float(__builtin_amdgcn_update_dpp(0, __float_as_int(x), 0x4E, 0xF, 0xF, true));
  x += __int_as_float(__builtin_amdgcn_update_dpp(0, __float_as_int(x), 0x141, 0xF, 0xF, true));
  x += __int_as_float(__builtin_amdgcn_update_dpp(0, __float_as_int(x), 0x140, 0xF, 0xF, true));
  return x;
}

// ---------------------------------------------------------------------------
// bf16 MFMA GEMM, 128x128 tile, m97 structure + mode-switched epilogue.
// ---------------------------------------------------------------------------
__global__ __launch_bounds__(256) void gemm_bf16(
    const ushort_t* __restrict__ A, const ushort_t* __restrict__ W,
    int M, int N, int K, int mode,
    float* __restrict__ f0, float* __restrict__ f1, float* __restrict__ f2,
    ushort_t* __restrict__ b0, ushort_t* __restrict__ b1,
    const float* __restrict__ bias, const float* __restrict__ A_log,
    const float* __restrict__ dt_bias) {
  __shared__ alignas(16) ushort_t As[4096];
  __shared__ alignas(16) ushort_t Bs[4096];
  __shared__ float l2s[2][128];
  const int tid = threadIdx.x;
  const int wv = tid >> 6, ln = tid & 63;
  const int bm = blockIdx.y * 128, bn = blockIdx.x * 128;
  const int wm = wv >> 1, wn = wv & 1;

  const int srow = tid >> 2;
  const int skg = (tid & 3) ^ ((srow >> 1) & 3);
  const size_t ag0 = (size_t)(bm + srow) * K + skg * 8;
  const size_t ag1 = ag0 + (size_t)64 * K;
  const size_t bg0 = (size_t)(bn + srow) * K + skg * 8;
  const size_t bg1 = bg0 + (size_t)64 * K;
  char* const lA = (char*)As;
  char* const lB = (char*)Bs;
  const int wbase = wv * 1024;

  const int fr = ln & 15, fq = ln >> 4;
  const int pg = fq ^ ((fr >> 1) & 3);
  int aoff[4], boff[4];
#pragma unroll
  for (int i = 0; i < 4; i++) {
    aoff[i] = (wm * 64 + i * 16 + fr) * 64 + pg * 16;
    boff[i] = (wn * 64 + i * 16 + fr) * 64 + pg * 16;
  }

  f32x4 acc[4][4];
#pragma unroll
  for (int i = 0; i < 4; i++)
#pragma unroll
    for (int j = 0; j < 4; j++) {
      acc[i][j][0] = 0.f; acc[i][j][1] = 0.f; acc[i][j][2] = 0.f; acc[i][j][3] = 0.f;
    }

  for (int k0 = 0; k0 < K; k0 += 32) {
    gld_lds16(A + ag0 + k0, lA + wbase);
    gld_lds16(A + ag1 + k0, lA + 4096 + wbase);
    gld_lds16(W + bg0 + k0, lB + wbase);
    gld_lds16(W + bg1 + k0, lB + 4096 + wbase);
    __syncthreads();
    short8 af[4], bf[4];
#pragma unroll
    for (int i = 0; i < 4; i++) af[i] = *(const short8*)(lA + aoff[i]);
#pragma unroll
    for (int i = 0; i < 4; i++) bf[i] = *(const short8*)(lB + boff[i]);
#pragma unroll
    for (int i = 0; i < 4; i++)
#pragma unroll
      for (int j = 0; j < 4; j++)
        acc[i][j] = __builtin_amdgcn_mfma_f32_16x16x32_bf16(af[i], bf[j], acc[i][j], 0, 0, 0);
    __syncthreads();
  }

  // C/D layout: col = ln&15, row = (ln>>4)*4 + reg
  const int cc = ln & 15, cq = ln >> 4;

  if (mode == M_QKV) {
    // silu in place
#pragma unroll
    for (int i = 0; i < 4; i++)
#pragma unroll
      for (int j = 0; j < 4; j++)
#pragma unroll
        for (int r = 0; r < 4; r++) acc[i][j][r] = silu(acc[i][j][r]);
    const bool isqk = (bn < 4096);
    float invr[4][4];
    if (isqk) {
      const float scale = (bn < 2048) ? 0.08838834764831845f : 1.0f;
#pragma unroll
      for (int i = 0; i < 4; i++)
#pragma unroll
        for (int r = 0; r < 4; r++) {
          float ss = 0.f;
#pragma unroll
          for (int j = 0; j < 4; j++) ss = fmaf(acc[i][j][r], acc[i][j][r], ss);
          ss = row16_sum(ss);
          if (cc == 0) l2s[wn][wm * 64 + i * 16 + cq * 4 + r] = ss;
        }
      __syncthreads();
#pragma unroll
      for (int i = 0; i < 4; i++)
#pragma unroll
        for (int r = 0; r < 4; r++) {
          const int rl = wm * 64 + i * 16 + cq * 4 + r;
          invr[i][r] = rsqrtf(l2s[0][rl] + l2s[1][rl] + 1e-6f) * scale;
        }
    } else {
#pragma unroll
      for (int i = 0; i < 4; i++)
#pragma unroll
        for (int r = 0; r < 4; r++) invr[i][r] = 1.f;
    }
    const int nb = bn & 2047;
#pragma unroll
    for (int i = 0; i < 4; i++)
#pragma unroll
      for (int r = 0; r < 4; r++) {
        const int gm = bm + wm * 64 + i * 16 + cq * 4 + r;
#pragma unroll
        for (int j = 0; j < 4; j++) {
          const int gn = nb + wn * 64 + j * 16 + cc;
          const float val = acc[i][j][r] * invr[i][r];
          if (bn < 4096) {   // q,k -> bf16
            ushort_t* db = (bn < 2048) ? b0 : b1;
            db[(size_t)gm * 2048 + gn] = f32_to_bf16(val);
          } else {           // v -> f32
            f2[(size_t)gm * 2048 + gn] = val;
          }
        }
      }
    return;
  }

  if (mode == M_LOWRANK) {
#pragma unroll
    for (int i = 0; i < 4; i++)
#pragma unroll
      for (int r = 0; r < 4; r++) {
        const int gm = bm + wm * 64 + i * 16 + cq * 4 + r;
#pragma unroll
        for (int j = 0; j < 4; j++) {
          const int gn = bn + wn * 64 + j * 16 + cc;
          const float x = acc[i][j][r];
          if (gn < 128) b0[(size_t)gm * 128 + gn] = f32_to_bf16(x);
          else if (gn < 256) b1[(size_t)gm * 128 + (gn - 128)] = f32_to_bf16(x);
          else if (gn < 272) f0[(size_t)gm * 16 + (gn - 256)] = 1.f / (1.f + __expf(-x));
        }
      }
    return;
  }

  // M_PLAIN / M_GATE / M_FACTOR -> f32, stride N
#pragma unroll
  for (int i = 0; i < 4; i++)
#pragma unroll
    for (int r = 0; r < 4; r++) {
      const int gm = bm + wm * 64 + i * 16 + cq * 4 + r;
#pragma unroll
      for (int j = 0; j < 4; j++) {
        const int gn = bn + wn * 64 + j * 16 + cc;
        float x = acc[i][j][r];
        if (mode == M_FACTOR) x += bias[gn];
        else if (mode == M_GATE) {
          const float y = x + dt_bias[gn];
          const float sp = fmaxf(y, 0.f) + log1pf(__expf(-fabsf(y)));
          x = __expf(-__expf(A_log[gn >> 7]) * sp);
        }
        f0[(size_t)gm * N + gn] = x;
      }
    }
}

__global__ __launch_bounds__(256) void cast_bf16(const float* __restrict__ x,
                                                 ushort_t* __restrict__ y, int n) {
  const int i = (blockIdx.x * 256 + threadIdx.x) * 4;
  if (i >= n) return;
  const float4 v = *(const float4*)&x[i];
  union { ushort_t u[4]; uint2 v2; } o;
  o.u[0] = f32_to_bf16(v.x); o.u[1] = f32_to_bf16(v.y);
  o.u[2] = f32_to_bf16(v.z); o.u[3] = f32_to_bf16(v.w);
  *(uint2*)&y[i] = o.v2;
}

// ---------------------------------------------------------------------------
// Barrier-free gated delta-rule scan, v10. bf16 k/q + f32 g staged via LDS.
// grid = 2048 (64 bh x 32 colgroups, XCD-swizzled), block = 64 (one wave).
// Lane: cl = ln>>4 (4 cols), kg = ln&15 (16-way k-split), S[8]/lane.
// LDS slot = 4 steps: k 1KB bf16 | q 1KB bf16 | g 2KB f32 (swizzled) = 4KB.
// 4 slots = 16-step horizon, 16KB. Restage/slot = 4 gld_lds16 + 4 v + 4 beta
// = 12 VMEM. Reads/step: k b128 + q b128 + g 2xb128. vmcnt peel 24/28/32/36
// then steady 36; lgkm wait 4; one-step read-ahead; all-SALU addressing.
// ---------------------------------------------------------------------------
__global__ __launch_bounds__(64, 2) void kda_scan(
    const ushort_t* __restrict__ q, const ushort_t* __restrict__ k,
    const float* __restrict__ v, const float* __restrict__ ge,
    const float* __restrict__ beta, const float* __restrict__ S0,
    float* __restrict__ o, float* __restrict__ S_out) {
  const int bid = blockIdx.x;
  const int bh = (((bid >> 3) & 7) << 3) | (bid & 7);
  const int cg = bid >> 6;
  const int h = bh & 15, b = bh >> 4;
  const int ln = threadIdx.x;
  const int cl = ln >> 4, kg = ln & 15;
  const int col = cg * 4 + cl;
  const int kof = kg * 8;

  __shared__ alignas(16) char lds[16384];

  const size_t s_base = (size_t)bh * (128 * 128);
  const size_t rb = (size_t)b * (2048 * 2048) + (size_t)h * 128;
  const size_t bbase = (size_t)(b * 2048) * 16 + h;

  // uniform bases, advanced in SALU inside the loop
  const char* kc = (const char*)k + rb * 2;     // bf16, row 4096B
  const char* qc = (const char*)q + rb * 2;
  const char* gc = (const char*)ge + rb * 4;    // f32, row 8192B
  const float* vbp = v + rb;
  const float* bbp = beta + bbase;
  float* obp = o + rb;
  const float* S0b = S0 + s_base;

  // staging sources:
  // k/q: lane L covers row L>>4 (of 4), bytes (L&15)*16 -> linear LDS rows.
  const unsigned lane_src_kq = (unsigned)((ln >> 4) * 4096 + (ln & 15) * 16);
  // g: v8-proven pre-swizzle; 1 gld covers 2 rows of 512B.
  const int cpos = ln & 31;
  const int gch = (cpos & ~1) | ((cpos & 1) ^ ((cpos >> 3) & 1));
  const unsigned lane_src_g = (unsigned)((ln >> 5) * 8192 + gch * 16);

  // read addresses
  const unsigned rdK = (unsigned)(kg * 16);                              // k/q
  const unsigned rd0g = (unsigned)(kg * 32 + ((0 ^ ((kg >> 2) & 1)) * 16));
  const unsigned rd1g = (unsigned)(kg * 32 + ((1 ^ ((kg >> 2) & 1)) * 16));

  // per-lane voffsets for v/o (row u at u*8192 bytes)
  const unsigned voff_v0 = (unsigned)(col * 4);
  const unsigned voff_v1 = voff_v0 + 8192u;
  const unsigned voff_v2 = voff_v0 + 16384u;
  const unsigned voff_v3 = voff_v0 + 24576u;
  const unsigned voff_b = 0u;

  // ---- initial state via asm loads ----------------------------------------
  float S[8];
#pragma unroll
  for (int j = 0; j < 8; ++j) {
    const unsigned offs = (unsigned)(((kof + j) * 128 + col) * 4);
    asm volatile("global_load_dword %0, %1, %2" : "=v"(S[j]) : "v"(offs), "s"(S0b));
  }

  float Vs[4][4], Bs[4][4], Os[4];
  int4v Kda, Qda, Kdb, Qdb;
  f32x4 G0a, G1a, G0b, G1b;

#define WAITV(N) do { asm volatile("s_waitcnt vmcnt(" #N ")" ::: "memory"); \
                      __builtin_amdgcn_sched_barrier(0); } while (0)
#define WAITL(N) do { asm volatile("s_waitcnt lgkmcnt(" #N ")" ::: "memory"); \
                      __builtin_amdgcn_sched_barrier(0); } while (0)
#define DSR(dst, a, IMM) \
  asm volatile("ds_read_b128 %0, %1 offset:%c2" : "=v"(dst) : "v"(a), "n"(IMM))

// 4 ds_reads for one step: slot SL, step PH, into fragment suffix SFX
#define READS(SFX, SL, PH)                                    \
  do {                                                        \
    DSR(Kd##SFX, rdK,  (SL)*4096 + (PH)*256);                 \
    DSR(Qd##SFX, rdK,  (SL)*4096 + 1024 + (PH)*256);          \
    DSR(G0##SFX, rd0g, (SL)*4096 + 2048 + (PH)*512);          \
    DSR(G1##SFX, rd1g, (SL)*4096 + 2048 + (PH)*512);          \
  } while (0)

// restage slot SL for +16 steps: 4 gld_lds16 + 4 v + 4 beta = 12 VMEM
#define RESTAGE(SL)                                                                                  \
  do {                                                                                               \
    gld_lds16(kc + lane_src_kq, lds + (SL)*4096);          kc += 16384;                              \
    gld_lds16(qc + lane_src_kq, lds + (SL)*4096 + 1024);   qc += 16384;                              \
    gld_lds16(gc + lane_src_g,  lds + (SL)*4096 + 2048);                                             \
    gld_lds16(gc + 16384 + lane_src_g, lds + (SL)*4096 + 3072); gc += 32768;                         \
    asm volatile("global_load_dword %0, %1, %2" : "=v"(Vs[SL][0]) : "v"(voff_v0), "s"(vbp));         \
    asm volatile("global_load_dword %0, %1, %2" : "=v"(Vs[SL][1]) : "v"(voff_v1), "s"(vbp));         \
    asm volatile("global_load_dword %0, %1, %2" : "=v"(Vs[SL][2]) : "v"(voff_v2), "s"(vbp));         \
    asm volatile("global_load_dword %0, %1, %2" : "=v"(Vs[SL][3]) : "v"(voff_v3), "s"(vbp));         \
    vbp += 8192;                                                                                     \
    asm volatile("global_load_dword %0, %1, %2"            : "=v"(Bs[SL][0]) : "v"(voff_b), "s"(bbp)); \
    asm volatile("global_load_dword %0, %1, %2 offset:64"  : "=v"(Bs[SL][1]) : "v"(voff_b), "s"(bbp)); \
    asm volatile("global_load_dword %0, %1, %2 offset:128" : "=v"(Bs[SL][2]) : "v"(voff_b), "s"(bbp)); \
    asm volatile("global_load_dword %0, %1, %2 offset:192" : "=v"(Bs[SL][3]) : "v"(voff_b), "s"(bbp)); \
    bbp += 64;                                                                                       \
  } while (0)

#define STORES(SL)                                                                                   \
  do {                                                                                               \
    if (kg == 0) {                                                                                   \
      asm volatile("global_store_dword %0, %1, %2" :: "v"(voff_v0), "v"(Os[0]), "s"(obp) : "memory"); \
      asm volatile("global_store_dword %0, %1, %2" :: "v"(voff_v1), "v"(Os[1]), "s"(obp) : "memory"); \
      asm volatile("global_store_dword %0, %1, %2" :: "v"(voff_v2), "v"(Os[2]), "s"(obp) : "memory"); \
      asm volatile("global_store_dword %0, %1, %2" :: "v"(voff_v3), "v"(Os[3]), "s"(obp) : "memory"); \
    }                                                                                                \
    obp += 8192;                                                                                     \
  } while (0)

#define COMPUTE(F, SS, U)                                                                            \
  do {                                                                                               \
    const int4v kd = Kd##F; const int4v qd = Qd##F;                                                  \
    const float k0 = __int_as_float(kd[0] << 16), k1 = __int_as_float(kd[0] & 0xffff0000);           \
    const float k2 = __int_as_float(kd[1] << 16), k3 = __int_as_float(kd[1] & 0xffff0000);           \
    const float k4 = __int_as_float(kd[2] << 16), k5 = __int_as_float(kd[2] & 0xffff0000);           \
    const float k6 = __int_as_float(kd[3] << 16), k7 = __int_as_float(kd[3] & 0xffff0000);           \
    const float q0 = __int_as_float(qd[0] << 16), q1 = __int_as_float(qd[0] & 0xffff0000);           \
    const float q2 = __int_as_float(qd[1] << 16), q3 = __int_as_float(qd[1] & 0xffff0000);           \
    const float q4 = __int_as_float(qd[2] << 16), q5 = __int_as_float(qd[2] & 0xffff0000);           \
    const float q6 = __int_as_float(qd[3] << 16), q7 = __int_as_float(qd[3] & 0xffff0000);           \
    float p0 = 0.f, p1 = 0.f, o0 = 0.f, o1 = 0.f, d0 = 0.f, d1 = 0.f;                                \
    S[0] *= G0##F[0]; p0 = fmaf(k0, S[0], p0); o0 = fmaf(q0, S[0], o0); d0 = fmaf(q0, k0, d0);       \
    S[1] *= G0##F[1]; p1 = fmaf(k1, S[1], p1); o1 = fmaf(q1, S[1], o1); d1 = fmaf(q1, k1, d1);       \
    S[2] *= G0##F[2]; p0 = fmaf(k2, S[2], p0); o0 = fmaf(q2, S[2], o0); d0 = fmaf(q2, k2, d0);       \
    S[3] *= G0##F[3]; p1 = fmaf(k3, S[3], p1); o1 = fmaf(q3, S[3], o1); d1 = fmaf(q3, k3, d1);       \
    S[4] *= G1##F[0]; p0 = fmaf(k4, S[4], p0); o0 = fmaf(q4, S[4], o0); d0 = fmaf(q4, k4, d0);       \
    S[5] *= G1##F[1]; p1 = fmaf(k5, S[5], p1); o1 = fmaf(q5, S[5], o1); d1 = fmaf(q5, k5, d1);       \
    S[6] *= G1##F[2]; p0 = fmaf(k6, S[6], p0); o0 = fmaf(q6, S[6], o0); d0 = fmaf(q6, k6, d0);       \
    S[7] *= G1##F[3]; p1 = fmaf(k7, S[7], p1); o1 = fmaf(q7, S[7], o1); d1 = fmaf(q7, k7, d1);       \
    const float p  = row16_sum(p0 + p1);                                                             \
    const float oq = row16_sum(o0 + o1);                                                             \
    const float qk = row16_sum(d0 + d1);                                                             \
    const float delta = (Vs[SS][U] - p) * Bs[SS][U];                                                 \
    Os[U] = fmaf(qk, delta, oq);                                                                     \
    S[0] = fmaf(k0, delta, S[0]);                                                                    \
    S[1] = fmaf(k1, delta, S[1]);                                                                    \
    S[2] = fmaf(k2, delta, S[2]);                                                                    \
    S[3] = fmaf(k3, delta, S[3]);                                                                    \
    S[4] = fmaf(k4, delta, S[4]);                                                                    \
    S[5] = fmaf(k5, delta, S[5]);                                                                    \
    S[6] = fmaf(k6, delta, S[6]);                                                                    \
    S[7] = fmaf(k7, delta, S[7]);                                                                    \
  } while (0)

// slot SL; NS = next slot; WV = u3 vmcnt keep-count
#define SLOT(SL, NS, WV)                                           \
  do {                                                             \
    READS(b, SL, 1); WAITL(4); COMPUTE(a, SL, 0);                  \
    READS(a, SL, 2); WAITL(4); COMPUTE(b, SL, 1);                  \
    READS(b, SL, 3); WAITL(4); COMPUTE(a, SL, 2);                  \
    WAITV(WV); READS(a, NS, 0); WAITL(4); COMPUTE(b, SL, 3);       \
    RESTAGE(SL); STORES(SL);                                       \
  } while (0)

#define ITER(W0, W1, W2, W3)                          \
  do {                                                \
    SLOT(0, 1, W0);                                   \
    SLOT(1, 2, W1);                                   \
    SLOT(2, 3, W2);                                   \
    SLOT(3, 0, W3);                                   \
  } while (0)

  // ---- prologue: stage slots 0..3 (steps 0..15) ---------------------------
  RESTAGE(0);
  RESTAGE(1);
  RESTAGE(2);
  RESTAGE(3);
  WAITV(36);               // drains S0(8)+slot0(12); keeps slots 1-3 (36)
  READS(a, 0, 0);          // step 0 fragments

  ITER(24, 28, 32, 36);    // peeled first iteration (prologue FIFO spacing)
  for (int it = 1; it < 128; ++it) {
    ITER(36, 36, 36, 36);
  }
  // final iteration's restages/reads over-run into adjacent allocated
  // workspace/output regions (<=128KB) and are never consumed.

  // drain everything before the compiler may reuse destination VGPRs
  WAITL(0);
  WAITV(0);

#pragma unroll
  for (int j = 0; j < 8; ++j)
    S_out[s_base + (size_t)(kof + j) * 128 + col] = S[j];

#undef ITER
#undef SLOT
#undef COMPUTE
#undef STORES
#undef RESTAGE
#undef READS
#undef DSR
#undef WAITL
#undef WAITV
}

// out_bf16 = rms(o)*w*sigmoid(factor). grid 2048 x 256: 64 rows/block.
__global__ __launch_bounds__(256) void gate_rmsnorm(
    const float* __restrict__ o, const float* __restrict__ factor,
    const float* __restrict__ w, ushort_t* __restrict__ out) {
  const int ln = threadIdx.x & 63, wv = threadIdx.x >> 6;
  const float w0 = w[ln * 2], w1 = w[ln * 2 + 1];
  const size_t row0 = (size_t)blockIdx.x * 64 + wv * 16;
  for (int it = 0; it < 16; it++) {
    const size_t base = (row0 + it) * 128 + ln * 2;
    const float2 x = *(const float2*)&o[base];
    const float2 f = *(const float2*)&factor[base];
    float ss = fmaf(x.x, x.x, x.y * x.y);
    ss = row16_sum(ss);
    ss += __shfl_xor(ss, 16);
    ss += __shfl_xor(ss, 32);
    const float r = rsqrtf(ss * (1.f / 128.f) + 1e-5f);
    const float y0 = x.x * r * w0 / (1.f + __expf(-f.x));
    const float y1 = x.y * r * w1 / (1.f + __expf(-f.y));
    *(unsigned int*)&out[base] =
        (unsigned int)f32_to_bf16(y0) | ((unsigned int)f32_to_bf16(y1) << 16);
  }
}

extern "C" void kernel_launch(void* const* d_in, const int* in_sizes, int n_in,
                              void* d_out, int out_size, void* d_ws, size_t ws_size,
                              hipStream_t stream) {
  const float* h    = (const float*)d_in[0];
  const float* S0   = (const float*)d_in[1];
  const float* q_w  = (const float*)d_in[2];
  const float* k_w  = (const float*)d_in[3];
  const float* v_w  = (const float*)d_in[4];
  const float* f_w0 = (const float*)d_in[5];
  const float* f_w1 = (const float*)d_in[6];
  const float* b_w  = (const float*)d_in[7];
  const float* A_log  = (const float*)d_in[8];
  const float* dt_b   = (const float*)d_in[9];
  const float* g_w0 = (const float*)d_in[10];
  const float* g_w1 = (const float*)d_in[11];
  const float* g_b1 = (const float*)d_in[12];
  const float* o_nw = (const float*)d_in[13];
  const float* o_w  = (const float*)d_in[14];

  float* outp = (float*)d_out;                 // exp(g) -> factor -> final out
  float* Sout = outp + (size_t)8192 * 2048;

  const size_t BIG = (size_t)8192 * 2048;   // 16.8M elems
  float* ws = (float*)d_ws;
  float* vbuf  = ws;                         // f32 [BIG]
  float* qbuf  = vbuf + BIG;                 // q bf16 lives here; gated bf16 reuses
  float* kbuf  = qbuf + BIG;                 // k bf16 lives here
  float* betab = kbuf + BIG;                 // f32 [8192*16]
  ushort_t* fpreb = (ushort_t*)(betab + (size_t)8192 * 16);   // bf16 [8192*128]
  ushort_t* gpreb = fpreb + (size_t)8192 * 128;
  ushort_t* wf1   = gpreb + (size_t)8192 * 128;               // [2048*128]
  ushort_t* wg1   = wf1 + (size_t)2048 * 128;
  ushort_t* wo    = wg1 + (size_t)2048 * 128;                 // [2048*2048]
  ushort_t* wlow  = wo + (size_t)2048 * 2048;                 // [384*2048]
  ushort_t* hb    = wlow + (size_t)384 * 2048;                // [BIG] bf16
  ushort_t* wqkv  = hb + BIG;                                 // [6144*2048] bf16
  // obuf (scan output, f32 BIG) aliases [hb | wqkv | pad] — all dead pre-scan
  float* obuf = (float*)hb;
  ushort_t* gatedb = (ushort_t*)qbuf;        // bf16 gated o (qbuf dead post-scan)
  ushort_t* qb16 = (ushort_t*)qbuf;          // bf16 q [8192*2048]
  ushort_t* kb16 = (ushort_t*)kbuf;          // bf16 k [8192*2048]

  const dim3 blk(256);

  // casts
  cast_bf16<<<16384, blk, 0, stream>>>(h, hb, 8192 * 2048);
  cast_bf16<<<4096, blk, 0, stream>>>(q_w, wqkv, 2048 * 2048);
  cast_bf16<<<4096, blk, 0, stream>>>(k_w, wqkv + (size_t)2048 * 2048, 2048 * 2048);
  cast_bf16<<<4096, blk, 0, stream>>>(v_w, wqkv + (size_t)4096 * 2048, 2048 * 2048);
  cast_bf16<<<4096, blk, 0, stream>>>(o_w, wo, 2048 * 2048);
  cast_bf16<<<256, blk, 0, stream>>>(f_w0, wlow, 128 * 2048);
  cast_bf16<<<256, blk, 0, stream>>>(g_w0, wlow + (size_t)128 * 2048, 128 * 2048);
  cast_bf16<<<32, blk, 0, stream>>>(b_w, wlow + (size_t)256 * 2048, 16 * 2048);
  cast_bf16<<<256, blk, 0, stream>>>(f_w1, wf1, 2048 * 128);
  cast_bf16<<<256, blk, 0, stream>>>(g_w1, wg1, 2048 * 128);

  // fused QKV projection: silu(+l2norm) -> q,k bf16; v f32
  gemm_bf16<<<dim3(48, 64), blk, 0, stream>>>(hb, wqkv, 8192, 6144, 2048, M_QKV,
      nullptr, nullptr, vbuf, qb16, kb16, nullptr, nullptr, nullptr);
  // fused lowrank: fpre|gpre (bf16) + beta (sigmoid f32)
  gemm_bf16<<<dim3(3, 64), blk, 0, stream>>>(hb, wlow, 8192, 384, 2048, M_LOWRANK,
      betab, nullptr, nullptr, fpreb, gpreb, nullptr, nullptr, nullptr);
  // exp(g) -> outp
  gemm_bf16<<<dim3(16, 64), blk, 0, stream>>>(fpreb, wf1, 8192, 2048, 128, M_GATE,
      outp, nullptr, nullptr, nullptr, nullptr, nullptr, A_log, dt_b);
  // scan: o -> obuf (hb/wqkv region dead), S -> d_out tail
  kda_scan<<<2048, 64, 0, stream>>>(qb16, kb16, vbuf, outp, betab, S0, obuf, Sout);
  // factor = gpre @ g_w1.T + g_b1 -> outp (exp(g) dead)
  gemm_bf16<<<dim3(16, 64), blk, 0, stream>>>(gpreb, wg1, 8192, 2048, 128, M_FACTOR,
      outp, nullptr, nullptr, nullptr, nullptr, g_b1, nullptr, nullptr);
  // gated rmsnorm -> bf16 into gatedb (qbuf region)
  gate_rmsnorm<<<2048, blk, 0, stream>>>(obuf, outp, o_nw, gatedb);
  // out = gated_o @ o_w.T -> outp
  gemm_bf16<<<dim3(16, 64), blk, 0, stream>>>(gatedb, wo, 8192, 2048, 2048, M_PLAIN,
      outp, nullptr, nullptr, nullptr, nullptr, nullptr, nullptr, nullptr);
}